// Round 1
// baseline (689.437 us; speedup 1.0000x reference)
//
#include <hip/hip_runtime.h>
#include <hip/hip_bf16.h>
#include <math.h>

#define Bdim 4
#define Sdim 100
#define Tdim 128
#define Cdim 256
#define Hdim 256
#define NHd  4
#define DHd  32
#define AHd  128

// ---------------------------------------------------------------- FIRE bias
__device__ __forceinline__ float fire_eval(float dist, float c,
                                           const float* __restrict__ w1,
                                           const float* __restrict__ w2,
                                           float maxd) {
  c = fmaxf(c, 0.0f);
  float d = logf(fmaf(c, dist, 1.0f)) / logf(fmaf(c, maxd, 1.0f));
  float acc = 0.0f;
#pragma unroll
  for (int j = 0; j < 32; ++j) {
    float x = d * w1[j];
    float h = x / (1.0f + expf(-x));   // silu
    acc = fmaf(h, w2[j], acc);
  }
  return acc;
}

__global__ __launch_bounds__(256) void fire_bias_kernel(
    const float* __restrict__ st_dist, const float* __restrict__ st_doy,
    const float* __restrict__ c_s, const float* __restrict__ w1_s, const float* __restrict__ w2_s,
    const float* __restrict__ c_t, const float* __restrict__ w1_t, const float* __restrict__ w2_t,
    const float* __restrict__ c_d, const float* __restrict__ w1_d, const float* __restrict__ w2_d,
    float* __restrict__ sb, float* __restrict__ tb, float* __restrict__ db) {
  int i = blockIdx.x * 256 + threadIdx.x;
  if (i >= Bdim * Tdim * Cdim) return;
  float2 dv = ((const float2*)st_dist)[i];
  sb[i] = fire_eval(dv.x, c_s[0], w1_s, w2_s, 180.0f);
  tb[i] = fire_eval(dv.y, c_t[0], w1_t, w2_t, 365.0f);
  db[i] = fire_eval(st_doy[i], c_d[0], w1_d, w2_d, 182.0f);
}

// ------------------------------------------------- generic f32 NT GEMM 64x128
// C[m][n0+n] = sum_k A[m][k] * W[n0+n][k] + bias[n0+n]
__global__ __launch_bounds__(256) void gemm_nt(
    const float* __restrict__ A, const float* __restrict__ W,
    const float* __restrict__ bias, float* __restrict__ C,
    int M, int N, int K) {
  __shared__ float as[16][68];
  __shared__ float ws[16][132];
  const int tid = threadIdx.x;
  const int m0 = blockIdx.x * 64;
  const int n0 = blockIdx.y * 128;
  const int lm = tid >> 2;          // 0..63
  const int kq = (tid & 3) << 2;    // 0,4,8,12
  const int ty = tid >> 4;          // 0..15
  const int tx = tid & 15;          // 0..15
  float acc[4][8] = {};
  for (int k0 = 0; k0 < K; k0 += 16) {
    float4 a4  = *(const float4*)(A + (size_t)(m0 + lm) * K + k0 + kq);
    float4 w4  = *(const float4*)(W + (size_t)(n0 + lm) * K + k0 + kq);
    float4 w4b = *(const float4*)(W + (size_t)(n0 + lm + 64) * K + k0 + kq);
    as[kq + 0][lm] = a4.x;  as[kq + 1][lm] = a4.y;  as[kq + 2][lm] = a4.z;  as[kq + 3][lm] = a4.w;
    ws[kq + 0][lm] = w4.x;  ws[kq + 1][lm] = w4.y;  ws[kq + 2][lm] = w4.z;  ws[kq + 3][lm] = w4.w;
    ws[kq + 0][lm + 64] = w4b.x; ws[kq + 1][lm + 64] = w4b.y;
    ws[kq + 2][lm + 64] = w4b.z; ws[kq + 3][lm + 64] = w4b.w;
    __syncthreads();
#pragma unroll
    for (int kk = 0; kk < 16; ++kk) {
      float4 af  = *(const float4*)&as[kk][ty << 2];
      float4 wf0 = *(const float4*)&ws[kk][tx << 3];
      float4 wf1 = *(const float4*)&ws[kk][(tx << 3) + 4];
      float a_[4] = {af.x, af.y, af.z, af.w};
      float w_[8] = {wf0.x, wf0.y, wf0.z, wf0.w, wf1.x, wf1.y, wf1.z, wf1.w};
#pragma unroll
      for (int i = 0; i < 4; ++i)
#pragma unroll
        for (int j = 0; j < 8; ++j)
          acc[i][j] = fmaf(a_[i], w_[j], acc[i][j]);
    }
    __syncthreads();
  }
#pragma unroll
  for (int i = 0; i < 4; ++i) {
    size_t row = (size_t)(m0 + (ty << 2) + i) * N + n0 + (tx << 3);
#pragma unroll
    for (int j = 0; j < 8; ++j)
      C[row + j] = acc[i][j] + bias[n0 + (tx << 3) + j];
  }
}

// -------------------------------------- fused K+V projection (A read once)
__global__ __launch_bounds__(256) void gemm_nt_kv(
    const float* __restrict__ A,
    const float* __restrict__ Wk, const float* __restrict__ bk,
    const float* __restrict__ Wv, const float* __restrict__ bv,
    float* __restrict__ Ko, float* __restrict__ Vo, int M, int K) {
  __shared__ float as[16][68];
  __shared__ float wks[16][132];
  __shared__ float wvs[16][132];
  const int tid = threadIdx.x;
  const int m0 = blockIdx.x * 64;
  const int lm = tid >> 2;
  const int kq = (tid & 3) << 2;
  const int ty = tid >> 4;
  const int tx = tid & 15;
  float acck[4][8] = {};
  float accv[4][8] = {};
  for (int k0 = 0; k0 < K; k0 += 16) {
    float4 a4   = *(const float4*)(A + (size_t)(m0 + lm) * K + k0 + kq);
    float4 wk4  = *(const float4*)(Wk + (size_t)lm * K + k0 + kq);
    float4 wk4b = *(const float4*)(Wk + (size_t)(lm + 64) * K + k0 + kq);
    float4 wv4  = *(const float4*)(Wv + (size_t)lm * K + k0 + kq);
    float4 wv4b = *(const float4*)(Wv + (size_t)(lm + 64) * K + k0 + kq);
    as[kq + 0][lm] = a4.x;  as[kq + 1][lm] = a4.y;  as[kq + 2][lm] = a4.z;  as[kq + 3][lm] = a4.w;
    wks[kq + 0][lm] = wk4.x; wks[kq + 1][lm] = wk4.y; wks[kq + 2][lm] = wk4.z; wks[kq + 3][lm] = wk4.w;
    wks[kq + 0][lm + 64] = wk4b.x; wks[kq + 1][lm + 64] = wk4b.y;
    wks[kq + 2][lm + 64] = wk4b.z; wks[kq + 3][lm + 64] = wk4b.w;
    wvs[kq + 0][lm] = wv4.x; wvs[kq + 1][lm] = wv4.y; wvs[kq + 2][lm] = wv4.z; wvs[kq + 3][lm] = wv4.w;
    wvs[kq + 0][lm + 64] = wv4b.x; wvs[kq + 1][lm + 64] = wv4b.y;
    wvs[kq + 2][lm + 64] = wv4b.z; wvs[kq + 3][lm + 64] = wv4b.w;
    __syncthreads();
#pragma unroll
    for (int kk = 0; kk < 16; ++kk) {
      float4 af  = *(const float4*)&as[kk][ty << 2];
      float4 k0f = *(const float4*)&wks[kk][tx << 3];
      float4 k1f = *(const float4*)&wks[kk][(tx << 3) + 4];
      float4 v0f = *(const float4*)&wvs[kk][tx << 3];
      float4 v1f = *(const float4*)&wvs[kk][(tx << 3) + 4];
      float a_[4] = {af.x, af.y, af.z, af.w};
      float wk_[8] = {k0f.x, k0f.y, k0f.z, k0f.w, k1f.x, k1f.y, k1f.z, k1f.w};
      float wv_[8] = {v0f.x, v0f.y, v0f.z, v0f.w, v1f.x, v1f.y, v1f.z, v1f.w};
#pragma unroll
      for (int i = 0; i < 4; ++i)
#pragma unroll
        for (int j = 0; j < 8; ++j) {
          acck[i][j] = fmaf(a_[i], wk_[j], acck[i][j]);
          accv[i][j] = fmaf(a_[i], wv_[j], accv[i][j]);
        }
    }
    __syncthreads();
  }
#pragma unroll
  for (int i = 0; i < 4; ++i) {
    size_t row = (size_t)(m0 + (ty << 2) + i) * 128 + (tx << 3);
#pragma unroll
    for (int j = 0; j < 8; ++j) {
      Ko[row + j] = acck[i][j] + bk[(tx << 3) + j];
      Vo[row + j] = accv[i][j] + bv[(tx << 3) + j];
    }
  }
}

// ------------------------------------------------------- fused attention
// one block per (b, s, h); 512 threads
__global__ __launch_bounds__(512) void attn_kernel(
    const float* __restrict__ Qp, const float* __restrict__ Kp, const float* __restrict__ Vp,
    const float* __restrict__ mask,
    const float* __restrict__ sb, const float* __restrict__ tb, const float* __restrict__ db,
    const float* __restrict__ sls, const float* __restrict__ tls,
    float* __restrict__ ctx) {
  __shared__ float ks[Cdim][33];   // b32-only reads, stride 33 -> conflict-free
  __shared__ float vs[Cdim][36];   // b128 reads, 16B aligned
  __shared__ float qs[32][36];
  __shared__ float ps[32][257];
  __shared__ float red[256][4];
  __shared__ float rinv[32];

  const int tid = threadIdx.x;
  const int bid = blockIdx.x;
  const int h = bid & 3;
  const int s = (bid >> 2) % Sdim;
  const int b = bid / (Sdim * NHd);
  const float es = __expf(sls[s]);
  const float et = __expf(tls[s]);

  const size_t kvbase = ((size_t)(b * Sdim + s)) * Cdim * AHd + h * DHd;
  // stage K and V (256 x 32 each)
#pragma unroll
  for (int r = 0; r < 4; ++r) {
    int slotq = r * 512 + tid;          // 0..2047 float4 slots
    int c = slotq >> 3;
    int q4 = (slotq & 7) << 2;
    float4 kv = *(const float4*)(Kp + kvbase + (size_t)c * AHd + q4);
    ks[c][q4 + 0] = kv.x; ks[c][q4 + 1] = kv.y; ks[c][q4 + 2] = kv.z; ks[c][q4 + 3] = kv.w;
    float4 vv = *(const float4*)(Vp + kvbase + (size_t)c * AHd + q4);
    *(float4*)&vs[c][q4] = vv;
  }
  __syncthreads();

  const int ccol = tid & 255;
  const int rh = tid >> 8;            // 0/1: row-half
  float kreg[32];
#pragma unroll
  for (int j = 0; j < 32; ++j) kreg[j] = ks[ccol][j];

  const size_t qbase = ((size_t)(b * Sdim + s)) * Tdim * AHd + h * DHd;
  const size_t mbase = ((size_t)b * Tdim) * Cdim;

  for (int t0 = 0; t0 < Tdim; t0 += 32) {
    if (tid < 256) {
      int t = tid >> 3, q4 = (tid & 7) << 2;
      float4 qv = *(const float4*)(Qp + qbase + (size_t)(t0 + t) * AHd + q4);
      *(float4*)&qs[t][q4] = qv;
    }
    __syncthreads();

    // phase A: scores (+bias, mask) for 32 rows; this thread owns column ccol
#pragma unroll 4
    for (int i = 0; i < 16; ++i) {
      int t = rh * 16 + i;
      float dot = 0.0f;
#pragma unroll
      for (int j8 = 0; j8 < 8; ++j8) {
        float4 qv = *(const float4*)&qs[t][j8 << 2];
        dot = fmaf(qv.x, kreg[4 * j8 + 0], dot);
        dot = fmaf(qv.y, kreg[4 * j8 + 1], dot);
        dot = fmaf(qv.z, kreg[4 * j8 + 2], dot);
        dot = fmaf(qv.w, kreg[4 * j8 + 3], dot);
      }
      size_t gi = mbase + (size_t)(t0 + t) * Cdim + ccol;
      float sc = fmaf(dot, 0.17677669529663687f, mask[gi]);
      sc = fmaf(sb[gi], es, sc);
      sc = fmaf(tb[gi], et, sc);
      sc += db[gi];
      ps[t][ccol] = sc;
    }
    __syncthreads();

    // softmax: 8 waves x 4 rows
    {
      const int wv_ = tid >> 6, lane = tid & 63;
#pragma unroll
      for (int rr = 0; rr < 4; ++rr) {
        int t = (wv_ << 2) + rr;
        float v0 = ps[t][lane], v1 = ps[t][lane + 64];
        float v2 = ps[t][lane + 128], v3 = ps[t][lane + 192];
        float mx = fmaxf(fmaxf(v0, v1), fmaxf(v2, v3));
#pragma unroll
        for (int off = 32; off > 0; off >>= 1) mx = fmaxf(mx, __shfl_xor(mx, off));
        float e0 = __expf(v0 - mx), e1 = __expf(v1 - mx);
        float e2 = __expf(v2 - mx), e3 = __expf(v3 - mx);
        float sm = e0 + e1 + e2 + e3;
#pragma unroll
        for (int off = 32; off > 0; off >>= 1) sm += __shfl_xor(sm, off);
        ps[t][lane] = e0; ps[t][lane + 64] = e1;
        ps[t][lane + 128] = e2; ps[t][lane + 192] = e3;
        if (lane == 0) rinv[t] = 1.0f / sm;
      }
    }
    __syncthreads();

    // phase B: PV. thread owns (t, 4 d's), c-range split in halves
    {
      const int chalf = tid >> 8;
      const int slot = tid & 255;
      const int t = slot >> 3;
      const int g4 = (slot & 7) << 2;
      const int cbase = chalf << 7;
      float4 a0 = {0, 0, 0, 0}, a1 = {0, 0, 0, 0};
#pragma unroll 4
      for (int cc = 0; cc < 128; cc += 2) {
        float p0 = ps[t][cbase + cc];
        float4 u0 = *(const float4*)&vs[cbase + cc][g4];
        a0.x = fmaf(p0, u0.x, a0.x); a0.y = fmaf(p0, u0.y, a0.y);
        a0.z = fmaf(p0, u0.z, a0.z); a0.w = fmaf(p0, u0.w, a0.w);
        float p1 = ps[t][cbase + cc + 1];
        float4 u1 = *(const float4*)&vs[cbase + cc + 1][g4];
        a1.x = fmaf(p1, u1.x, a1.x); a1.y = fmaf(p1, u1.y, a1.y);
        a1.z = fmaf(p1, u1.z, a1.z); a1.w = fmaf(p1, u1.w, a1.w);
      }
      if (chalf) {
        red[slot][0] = a0.x + a1.x; red[slot][1] = a0.y + a1.y;
        red[slot][2] = a0.z + a1.z; red[slot][3] = a0.w + a1.w;
      }
      __syncthreads();
      if (!chalf) {
        float r = rinv[t];
        float4 res;
        res.x = (a0.x + a1.x + red[slot][0]) * r;
        res.y = (a0.y + a1.y + red[slot][1]) * r;
        res.z = (a0.z + a1.z + red[slot][2]) * r;
        res.w = (a0.w + a1.w + red[slot][3]) * r;
        *(float4*)(ctx + qbase + (size_t)(t0 + t) * AHd + g4) = res;
      }
    }
    __syncthreads();
  }
}

// ------------------------------------------------------------------ launch
extern "C" void kernel_launch(void* const* d_in, const int* in_sizes, int n_in,
                              void* d_out, int out_size, void* d_ws, size_t ws_size,
                              hipStream_t stream) {
  const float* hs     = (const float*)d_in[0];
  const float* se     = (const float*)d_in[1];
  const float* mask   = (const float*)d_in[2];
  const float* stdist = (const float*)d_in[3];
  const float* stdoy  = (const float*)d_in[4];
  const float* Wq = (const float*)d_in[5];
  const float* bq = (const float*)d_in[6];
  const float* Wk = (const float*)d_in[7];
  const float* bk = (const float*)d_in[8];
  const float* Wv = (const float*)d_in[9];
  const float* bv = (const float*)d_in[10];
  const float* Wo = (const float*)d_in[11];
  const float* bo = (const float*)d_in[12];
  const float* c_s  = (const float*)d_in[13];
  const float* w1_s = (const float*)d_in[14];
  const float* w2_s = (const float*)d_in[15];
  const float* c_t  = (const float*)d_in[16];
  const float* w1_t = (const float*)d_in[17];
  const float* w2_t = (const float*)d_in[18];
  const float* c_d  = (const float*)d_in[19];
  const float* w1_d = (const float*)d_in[20];
  const float* w2_d = (const float*)d_in[21];
  const float* sls  = (const float*)d_in[22];
  const float* tls  = (const float*)d_in[23];
  float* out = (float*)d_out;

  float* ws = (float*)d_ws;
  const size_t BTC = (size_t)Bdim * Tdim * Cdim;            // 131072
  float* sb = ws;
  float* tb = sb + BTC;
  float* db = tb + BTC;
  float* Qp = db + BTC;                                     // (B,S,T,128)
  float* Kp = Qp + (size_t)Bdim * Sdim * Tdim * AHd;        // (B,S,C,128)
  float* Vp = Kp + (size_t)Bdim * Sdim * Cdim * AHd;
  float* ctxp = Vp + (size_t)Bdim * Sdim * Cdim * AHd;      // (B,S,T,128)

  const int MQ  = Bdim * Sdim * Tdim;   // 51200
  const int MKV = Bdim * Sdim * Cdim;   // 102400

  fire_bias_kernel<<<(Bdim * Tdim * Cdim + 255) / 256, 256, 0, stream>>>(
      stdist, stdoy, c_s, w1_s, w2_s, c_t, w1_t, w2_t, c_d, w1_d, w2_d, sb, tb, db);

  gemm_nt<<<dim3(MQ / 64, 1), 256, 0, stream>>>(hs, Wq, bq, Qp, MQ, 128, 256);
  gemm_nt_kv<<<dim3(MKV / 64), 256, 0, stream>>>(se, Wk, bk, Wv, bv, Kp, Vp, MKV, 256);

  attn_kernel<<<dim3(Bdim * Sdim * NHd), 512, 0, stream>>>(
      Qp, Kp, Vp, mask, sb, tb, db, sls, tls, ctxp);

  gemm_nt<<<dim3(MQ / 64, 2), 256, 0, stream>>>(ctxp, Wo, bo, out, MQ, 256, 128);
}

// Round 2
// 639.296 us; speedup vs baseline: 1.0784x; 1.0784x over previous
//
#include <hip/hip_runtime.h>
#include <hip/hip_bf16.h>
#include <math.h>

#define Bdim 4
#define Sdim 100
#define Tdim 128
#define Cdim 256
#define Hdim 256
#define NHd  4
#define DHd  32
#define AHd  128

// ---------------------------------------------------------------- FIRE bias
__device__ __forceinline__ float fire_eval(float dist, float c,
                                           const float* __restrict__ w1,
                                           const float* __restrict__ w2,
                                           float maxd) {
  c = fmaxf(c, 0.0f);
  float d = logf(fmaf(c, dist, 1.0f)) / logf(fmaf(c, maxd, 1.0f));
  float acc = 0.0f;
#pragma unroll
  for (int j = 0; j < 32; ++j) {
    float x = d * w1[j];
    float h = x / (1.0f + expf(-x));   // silu
    acc = fmaf(h, w2[j], acc);
  }
  return acc;
}

// writes sb, tb, and (db + mask) -- mask folded so attn does 3 loads not 4
__global__ __launch_bounds__(256) void fire_bias_kernel(
    const float* __restrict__ st_dist, const float* __restrict__ st_doy,
    const float* __restrict__ mask,
    const float* __restrict__ c_s, const float* __restrict__ w1_s, const float* __restrict__ w2_s,
    const float* __restrict__ c_t, const float* __restrict__ w1_t, const float* __restrict__ w2_t,
    const float* __restrict__ c_d, const float* __restrict__ w1_d, const float* __restrict__ w2_d,
    float* __restrict__ sb, float* __restrict__ tb, float* __restrict__ dbm) {
  int i = blockIdx.x * 256 + threadIdx.x;
  if (i >= Bdim * Tdim * Cdim) return;
  float2 dv = ((const float2*)st_dist)[i];
  sb[i] = fire_eval(dv.x, c_s[0], w1_s, w2_s, 180.0f);
  tb[i] = fire_eval(dv.y, c_t[0], w1_t, w2_t, 365.0f);
  dbm[i] = fire_eval(st_doy[i], c_d[0], w1_d, w2_d, 182.0f) + mask[i];
}

// ------------------------------------------------- generic f32 NT GEMM 64x128
__global__ __launch_bounds__(256) void gemm_nt(
    const float* __restrict__ A, const float* __restrict__ W,
    const float* __restrict__ bias, float* __restrict__ C,
    int M, int N, int K) {
  __shared__ float as[16][68];
  __shared__ float ws[16][132];
  const int tid = threadIdx.x;
  const int m0 = blockIdx.x * 64;
  const int n0 = blockIdx.y * 128;
  const int lm = tid >> 2;
  const int kq = (tid & 3) << 2;
  const int ty = tid >> 4;
  const int tx = tid & 15;
  float acc[4][8] = {};
  for (int k0 = 0; k0 < K; k0 += 16) {
    float4 a4  = *(const float4*)(A + (size_t)(m0 + lm) * K + k0 + kq);
    float4 w4  = *(const float4*)(W + (size_t)(n0 + lm) * K + k0 + kq);
    float4 w4b = *(const float4*)(W + (size_t)(n0 + lm + 64) * K + k0 + kq);
    as[kq + 0][lm] = a4.x;  as[kq + 1][lm] = a4.y;  as[kq + 2][lm] = a4.z;  as[kq + 3][lm] = a4.w;
    ws[kq + 0][lm] = w4.x;  ws[kq + 1][lm] = w4.y;  ws[kq + 2][lm] = w4.z;  ws[kq + 3][lm] = w4.w;
    ws[kq + 0][lm + 64] = w4b.x; ws[kq + 1][lm + 64] = w4b.y;
    ws[kq + 2][lm + 64] = w4b.z; ws[kq + 3][lm + 64] = w4b.w;
    __syncthreads();
#pragma unroll
    for (int kk = 0; kk < 16; ++kk) {
      float4 af  = *(const float4*)&as[kk][ty << 2];
      float4 wf0 = *(const float4*)&ws[kk][tx << 3];
      float4 wf1 = *(const float4*)&ws[kk][(tx << 3) + 4];
      float a_[4] = {af.x, af.y, af.z, af.w};
      float w_[8] = {wf0.x, wf0.y, wf0.z, wf0.w, wf1.x, wf1.y, wf1.z, wf1.w};
#pragma unroll
      for (int i = 0; i < 4; ++i)
#pragma unroll
        for (int j = 0; j < 8; ++j)
          acc[i][j] = fmaf(a_[i], w_[j], acc[i][j]);
    }
    __syncthreads();
  }
#pragma unroll
  for (int i = 0; i < 4; ++i) {
    size_t row = (size_t)(m0 + (ty << 2) + i) * N + n0 + (tx << 3);
#pragma unroll
    for (int j = 0; j < 8; ++j)
      C[row + j] = acc[i][j] + bias[n0 + (tx << 3) + j];
  }
}

// -------------------------------------- fused K+V projection (A read once)
__global__ __launch_bounds__(256) void gemm_nt_kv(
    const float* __restrict__ A,
    const float* __restrict__ Wk, const float* __restrict__ bk,
    const float* __restrict__ Wv, const float* __restrict__ bv,
    float* __restrict__ Ko, float* __restrict__ Vo, int M, int K) {
  __shared__ float as[16][68];
  __shared__ float wks[16][132];
  __shared__ float wvs[16][132];
  const int tid = threadIdx.x;
  const int m0 = blockIdx.x * 64;
  const int lm = tid >> 2;
  const int kq = (tid & 3) << 2;
  const int ty = tid >> 4;
  const int tx = tid & 15;
  float acck[4][8] = {};
  float accv[4][8] = {};
  for (int k0 = 0; k0 < K; k0 += 16) {
    float4 a4   = *(const float4*)(A + (size_t)(m0 + lm) * K + k0 + kq);
    float4 wk4  = *(const float4*)(Wk + (size_t)lm * K + k0 + kq);
    float4 wk4b = *(const float4*)(Wk + (size_t)(lm + 64) * K + k0 + kq);
    float4 wv4  = *(const float4*)(Wv + (size_t)lm * K + k0 + kq);
    float4 wv4b = *(const float4*)(Wv + (size_t)(lm + 64) * K + k0 + kq);
    as[kq + 0][lm] = a4.x;  as[kq + 1][lm] = a4.y;  as[kq + 2][lm] = a4.z;  as[kq + 3][lm] = a4.w;
    wks[kq + 0][lm] = wk4.x; wks[kq + 1][lm] = wk4.y; wks[kq + 2][lm] = wk4.z; wks[kq + 3][lm] = wk4.w;
    wks[kq + 0][lm + 64] = wk4b.x; wks[kq + 1][lm + 64] = wk4b.y;
    wks[kq + 2][lm + 64] = wk4b.z; wks[kq + 3][lm + 64] = wk4b.w;
    wvs[kq + 0][lm] = wv4.x; wvs[kq + 1][lm] = wv4.y; wvs[kq + 2][lm] = wv4.z; wvs[kq + 3][lm] = wv4.w;
    wvs[kq + 0][lm + 64] = wv4b.x; wvs[kq + 1][lm + 64] = wv4b.y;
    wvs[kq + 2][lm + 64] = wv4b.z; wvs[kq + 3][lm + 64] = wv4b.w;
    __syncthreads();
#pragma unroll
    for (int kk = 0; kk < 16; ++kk) {
      float4 af  = *(const float4*)&as[kk][ty << 2];
      float4 k0f = *(const float4*)&wks[kk][tx << 3];
      float4 k1f = *(const float4*)&wks[kk][(tx << 3) + 4];
      float4 v0f = *(const float4*)&wvs[kk][tx << 3];
      float4 v1f = *(const float4*)&wvs[kk][(tx << 3) + 4];
      float a_[4] = {af.x, af.y, af.z, af.w};
      float wk_[8] = {k0f.x, k0f.y, k0f.z, k0f.w, k1f.x, k1f.y, k1f.z, k1f.w};
      float wv_[8] = {v0f.x, v0f.y, v0f.z, v0f.w, v1f.x, v1f.y, v1f.z, v1f.w};
#pragma unroll
      for (int i = 0; i < 4; ++i)
#pragma unroll
        for (int j = 0; j < 8; ++j) {
          acck[i][j] = fmaf(a_[i], wk_[j], acck[i][j]);
          accv[i][j] = fmaf(a_[i], wv_[j], accv[i][j]);
        }
    }
    __syncthreads();
  }
#pragma unroll
  for (int i = 0; i < 4; ++i) {
    size_t row = (size_t)(m0 + (ty << 2) + i) * 128 + (tx << 3);
#pragma unroll
    for (int j = 0; j < 8; ++j) {
      Ko[row + j] = acck[i][j] + bk[(tx << 3) + j];
      Vo[row + j] = accv[i][j] + bv[(tx << 3) + j];
    }
  }
}

// ------------------------------------------------------- fused attention
// one block per (b, s, h); 512 threads. LDS: union of ks with ps/red/rinv
// => 78976 B -> 2 blocks/CU (was 112640 B -> 1 block/CU).
__global__ __launch_bounds__(512) void attn_kernel(
    const float* __restrict__ Qp, const float* __restrict__ Kp, const float* __restrict__ Vp,
    const float* __restrict__ sb, const float* __restrict__ tb, const float* __restrict__ dbm,
    const float* __restrict__ sls, const float* __restrict__ tls,
    float* __restrict__ ctx) {
  __shared__ float smem[19744];
  float* vs_   = smem;                     // [256][36] V, b128 reads
  float* qs_   = smem + 9216;              // [32][36]  Q tile
  float* ks_   = smem + 10368;             // [256][33] K staging (dead after kreg)
  float* ps_   = smem + 10368;             // [32][260] scores (union with ks_)
  float* red_  = smem + 10368 + 8320;      // [256][4]  c-half reduction (float4)
  float* rinv_ = smem + 10368 + 8320 + 1024; // [32]

  const int tid = threadIdx.x;
  const int bid = blockIdx.x;
  const int h = bid & 3;
  const int s = (bid >> 2) % Sdim;
  const int b = bid / (Sdim * NHd);
  const float es = __expf(sls[s]);
  const float et = __expf(tls[s]);

  const size_t kvbase = ((size_t)(b * Sdim + s)) * Cdim * AHd + h * DHd;
#pragma unroll
  for (int r = 0; r < 4; ++r) {
    int slotq = r * 512 + tid;          // 0..2047 float4 slots
    int c = slotq >> 3;
    int q4 = (slotq & 7) << 2;
    float4 kv = *(const float4*)(Kp + kvbase + (size_t)c * AHd + q4);
    ks_[c * 33 + q4 + 0] = kv.x; ks_[c * 33 + q4 + 1] = kv.y;
    ks_[c * 33 + q4 + 2] = kv.z; ks_[c * 33 + q4 + 3] = kv.w;
    float4 vv = *(const float4*)(Vp + kvbase + (size_t)c * AHd + q4);
    *(float4*)&vs_[c * 36 + q4] = vv;
  }
  __syncthreads();

  const int ccol = tid & 255;
  const int rh = tid >> 8;            // 0/1: row-half
  float kreg[32];
#pragma unroll
  for (int j = 0; j < 32; ++j) kreg[j] = ks_[ccol * 33 + j];
  __syncthreads();                    // ks_ dead; ps_ may now reuse the space

  const size_t qbase = ((size_t)(b * Sdim + s)) * Tdim * AHd + h * DHd;
  const size_t mbase = ((size_t)b * Tdim) * Cdim;

  for (int t0 = 0; t0 < Tdim; t0 += 32) {
    if (tid < 256) {
      int t = tid >> 3, q4 = (tid & 7) << 2;
      float4 qv = *(const float4*)(Qp + qbase + (size_t)(t0 + t) * AHd + q4);
      *(float4*)&qs_[t * 36 + q4] = qv;
    }
    __syncthreads();

    // phase A: scores (+bias) for 32 rows; this thread owns column ccol
#pragma unroll 4
    for (int i = 0; i < 16; ++i) {
      int t = rh * 16 + i;
      float dot = 0.0f;
#pragma unroll
      for (int j8 = 0; j8 < 8; ++j8) {
        float4 qv = *(const float4*)&qs_[t * 36 + (j8 << 2)];
        dot = fmaf(qv.x, kreg[4 * j8 + 0], dot);
        dot = fmaf(qv.y, kreg[4 * j8 + 1], dot);
        dot = fmaf(qv.z, kreg[4 * j8 + 2], dot);
        dot = fmaf(qv.w, kreg[4 * j8 + 3], dot);
      }
      size_t gi = mbase + (size_t)(t0 + t) * Cdim + ccol;
      float sc = fmaf(dot, 0.17677669529663687f, dbm[gi]);
      sc = fmaf(sb[gi], es, sc);
      sc = fmaf(tb[gi], et, sc);
      ps_[t * 260 + ccol] = sc;
    }
    __syncthreads();

    // softmax: 8 waves x 4 rows
    {
      const int wv_ = tid >> 6, lane = tid & 63;
#pragma unroll
      for (int rr = 0; rr < 4; ++rr) {
        int t = (wv_ << 2) + rr;
        float v0 = ps_[t * 260 + lane],       v1 = ps_[t * 260 + lane + 64];
        float v2 = ps_[t * 260 + lane + 128], v3 = ps_[t * 260 + lane + 192];
        float mx = fmaxf(fmaxf(v0, v1), fmaxf(v2, v3));
#pragma unroll
        for (int off = 32; off > 0; off >>= 1) mx = fmaxf(mx, __shfl_xor(mx, off));
        float e0 = __expf(v0 - mx), e1 = __expf(v1 - mx);
        float e2 = __expf(v2 - mx), e3 = __expf(v3 - mx);
        float sm = e0 + e1 + e2 + e3;
#pragma unroll
        for (int off = 32; off > 0; off >>= 1) sm += __shfl_xor(sm, off);
        ps_[t * 260 + lane] = e0;       ps_[t * 260 + lane + 64] = e1;
        ps_[t * 260 + lane + 128] = e2; ps_[t * 260 + lane + 192] = e3;
        if (lane == 0) rinv_[t] = 1.0f / sm;
      }
    }
    __syncthreads();

    // phase B: PV. thread owns (t, 4 d's), c-range split in halves
    {
      const int chalf = tid >> 8;
      const int slot = tid & 255;
      const int t = slot >> 3;
      const int g4 = (slot & 7) << 2;
      const int cbase = chalf << 7;
      float4 a0 = {0, 0, 0, 0}, a1 = {0, 0, 0, 0};
#pragma unroll 4
      for (int cc = 0; cc < 128; cc += 2) {
        float p0 = ps_[t * 260 + cbase + cc];
        float4 u0 = *(const float4*)&vs_[(cbase + cc) * 36 + g4];
        a0.x = fmaf(p0, u0.x, a0.x); a0.y = fmaf(p0, u0.y, a0.y);
        a0.z = fmaf(p0, u0.z, a0.z); a0.w = fmaf(p0, u0.w, a0.w);
        float p1 = ps_[t * 260 + cbase + cc + 1];
        float4 u1 = *(const float4*)&vs_[(cbase + cc + 1) * 36 + g4];
        a1.x = fmaf(p1, u1.x, a1.x); a1.y = fmaf(p1, u1.y, a1.y);
        a1.z = fmaf(p1, u1.z, a1.z); a1.w = fmaf(p1, u1.w, a1.w);
      }
      if (chalf) {
        float4 rr;
        rr.x = a0.x + a1.x; rr.y = a0.y + a1.y;
        rr.z = a0.z + a1.z; rr.w = a0.w + a1.w;
        *(float4*)&red_[slot * 4] = rr;
      }
      __syncthreads();
      if (!chalf) {
        float r = rinv_[t];
        float4 rr = *(const float4*)&red_[slot * 4];
        float4 res;
        res.x = (a0.x + a1.x + rr.x) * r;
        res.y = (a0.y + a1.y + rr.y) * r;
        res.z = (a0.z + a1.z + rr.z) * r;
        res.w = (a0.w + a1.w + rr.w) * r;
        *(float4*)(ctx + qbase + (size_t)(t0 + t) * AHd + g4) = res;
      }
    }
    __syncthreads();
  }
}

// ------------------------------------------------------------------ launch
extern "C" void kernel_launch(void* const* d_in, const int* in_sizes, int n_in,
                              void* d_out, int out_size, void* d_ws, size_t ws_size,
                              hipStream_t stream) {
  const float* hs     = (const float*)d_in[0];
  const float* se     = (const float*)d_in[1];
  const float* mask   = (const float*)d_in[2];
  const float* stdist = (const float*)d_in[3];
  const float* stdoy  = (const float*)d_in[4];
  const float* Wq = (const float*)d_in[5];
  const float* bq = (const float*)d_in[6];
  const float* Wk = (const float*)d_in[7];
  const float* bk = (const float*)d_in[8];
  const float* Wv = (const float*)d_in[9];
  const float* bv = (const float*)d_in[10];
  const float* Wo = (const float*)d_in[11];
  const float* bo = (const float*)d_in[12];
  const float* c_s  = (const float*)d_in[13];
  const float* w1_s = (const float*)d_in[14];
  const float* w2_s = (const float*)d_in[15];
  const float* c_t  = (const float*)d_in[16];
  const float* w1_t = (const float*)d_in[17];
  const float* w2_t = (const float*)d_in[18];
  const float* c_d  = (const float*)d_in[19];
  const float* w1_d = (const float*)d_in[20];
  const float* w2_d = (const float*)d_in[21];
  const float* sls  = (const float*)d_in[22];
  const float* tls  = (const float*)d_in[23];
  float* out = (float*)d_out;

  float* ws = (float*)d_ws;
  const size_t BTC = (size_t)Bdim * Tdim * Cdim;            // 131072
  float* sb = ws;
  float* tb = sb + BTC;
  float* dbm = tb + BTC;
  float* Qp = dbm + BTC;                                    // (B,S,T,128)
  float* Kp = Qp + (size_t)Bdim * Sdim * Tdim * AHd;        // (B,S,C,128)
  float* Vp = Kp + (size_t)Bdim * Sdim * Cdim * AHd;
  float* ctxp = Vp + (size_t)Bdim * Sdim * Cdim * AHd;      // (B,S,T,128)

  const int MQ  = Bdim * Sdim * Tdim;   // 51200
  const int MKV = Bdim * Sdim * Cdim;   // 102400

  fire_bias_kernel<<<(Bdim * Tdim * Cdim + 255) / 256, 256, 0, stream>>>(
      stdist, stdoy, mask, c_s, w1_s, w2_s, c_t, w1_t, w2_t, c_d, w1_d, w2_d, sb, tb, dbm);

  gemm_nt<<<dim3(MQ / 64, 1), 256, 0, stream>>>(hs, Wq, bq, Qp, MQ, 128, 256);
  gemm_nt_kv<<<dim3(MKV / 64), 256, 0, stream>>>(se, Wk, bk, Wv, bv, Kp, Vp, MKV, 256);

  attn_kernel<<<dim3(Bdim * Sdim * NHd), 512, 0, stream>>>(
      Qp, Kp, Vp, sb, tb, dbm, sls, tls, ctxp);

  gemm_nt<<<dim3(MQ / 64, 2), 256, 0, stream>>>(ctxp, Wo, bo, out, MQ, 256, 128);
}

// Round 3
// 391.384 us; speedup vs baseline: 1.7615x; 1.6334x over previous
//
#include <hip/hip_runtime.h>
#include <hip/hip_bf16.h>
#include <math.h>

#define Bdim 4
#define Sdim 100
#define Tdim 128
#define Cdim 256
#define Hdim 256
#define NHd  4
#define DHd  32
#define AHd  128

typedef short bf16x8 __attribute__((ext_vector_type(8)));
typedef float f32x4 __attribute__((ext_vector_type(4)));

// f32 -> bf16 (RNE) as raw short
__device__ __forceinline__ short f2b(float x) {
  unsigned u = __float_as_uint(x);
  unsigned r = (u + 0x7FFF + ((u >> 16) & 1)) >> 16;
  return (short)r;
}

// ---------------------------------------------------------------- FIRE bias
__device__ __forceinline__ float fire_eval(float dist, float c,
                                           const float* __restrict__ w1,
                                           const float* __restrict__ w2,
                                           float maxd) {
  c = fmaxf(c, 0.0f);
  float d = logf(fmaf(c, dist, 1.0f)) / logf(fmaf(c, maxd, 1.0f));
  float acc = 0.0f;
#pragma unroll
  for (int j = 0; j < 32; ++j) {
    float x = d * w1[j];
    float h = x / (1.0f + expf(-x));   // silu
    acc = fmaf(h, w2[j], acc);
  }
  return acc;
}

// sb, tb, (db+mask) over (B,T,C)
__global__ __launch_bounds__(256) void fire_bias_kernel(
    const float* __restrict__ st_dist, const float* __restrict__ st_doy,
    const float* __restrict__ mask,
    const float* __restrict__ c_s, const float* __restrict__ w1_s, const float* __restrict__ w2_s,
    const float* __restrict__ c_t, const float* __restrict__ w1_t, const float* __restrict__ w2_t,
    const float* __restrict__ c_d, const float* __restrict__ w1_d, const float* __restrict__ w2_d,
    float* __restrict__ sb, float* __restrict__ tb, float* __restrict__ dbm) {
  int i = blockIdx.x * 256 + threadIdx.x;
  if (i >= Bdim * Tdim * Cdim) return;
  float2 dv = ((const float2*)st_dist)[i];
  sb[i] = fire_eval(dv.x, c_s[0], w1_s, w2_s, 180.0f);
  tb[i] = fire_eval(dv.y, c_t[0], w1_t, w2_t, 365.0f);
  dbm[i] = fire_eval(st_doy[i], c_d[0], w1_d, w2_d, 182.0f) + mask[i];
}

// combined bias (B,S,T,C) = sb*es + tb*et + dbm   (es/et per species s)
__global__ __launch_bounds__(256) void bias_expand(
    const float* __restrict__ sb, const float* __restrict__ tb,
    const float* __restrict__ dbm,
    const float* __restrict__ sls, const float* __restrict__ tls,
    float* __restrict__ bias) {
  int by = blockIdx.y;              // b*S + s
  int s = by % Sdim, b = by / Sdim;
  float es = __expf(sls[s]), et = __expf(tls[s]);
  int o = blockIdx.x * 1024 + threadIdx.x * 4;
  size_t src = (size_t)b * Tdim * Cdim + o;
  float4 sv = *(const float4*)(sb + src);
  float4 tv = *(const float4*)(tb + src);
  float4 dv = *(const float4*)(dbm + src);
  float4 r;
  r.x = fmaf(sv.x, es, fmaf(tv.x, et, dv.x));
  r.y = fmaf(sv.y, es, fmaf(tv.y, et, dv.y));
  r.z = fmaf(sv.z, es, fmaf(tv.z, et, dv.z));
  r.w = fmaf(sv.w, es, fmaf(tv.w, et, dv.w));
  *(float4*)(bias + (size_t)by * Tdim * Cdim + o) = r;
}

// ------------------------------------------------- f32 NT GEMM, bf16 output
__global__ __launch_bounds__(256) void gemm_nt_b16(
    const float* __restrict__ A, const float* __restrict__ W,
    const float* __restrict__ bias, short* __restrict__ C,
    int M, int K, float scale) {   // N fixed = 128
  __shared__ float as[16][68];
  __shared__ float ws[16][132];
  const int tid = threadIdx.x;
  const int m0 = blockIdx.x * 64;
  const int lm = tid >> 2;
  const int kq = (tid & 3) << 2;
  const int ty = tid >> 4;
  const int tx = tid & 15;
  float acc[4][8] = {};
  for (int k0 = 0; k0 < K; k0 += 16) {
    float4 a4  = *(const float4*)(A + (size_t)(m0 + lm) * K + k0 + kq);
    float4 w4  = *(const float4*)(W + (size_t)lm * K + k0 + kq);
    float4 w4b = *(const float4*)(W + (size_t)(lm + 64) * K + k0 + kq);
    as[kq + 0][lm] = a4.x;  as[kq + 1][lm] = a4.y;  as[kq + 2][lm] = a4.z;  as[kq + 3][lm] = a4.w;
    ws[kq + 0][lm] = w4.x;  ws[kq + 1][lm] = w4.y;  ws[kq + 2][lm] = w4.z;  ws[kq + 3][lm] = w4.w;
    ws[kq + 0][lm + 64] = w4b.x; ws[kq + 1][lm + 64] = w4b.y;
    ws[kq + 2][lm + 64] = w4b.z; ws[kq + 3][lm + 64] = w4b.w;
    __syncthreads();
#pragma unroll
    for (int kk = 0; kk < 16; ++kk) {
      float4 af  = *(const float4*)&as[kk][ty << 2];
      float4 wf0 = *(const float4*)&ws[kk][tx << 3];
      float4 wf1 = *(const float4*)&ws[kk][(tx << 3) + 4];
      float a_[4] = {af.x, af.y, af.z, af.w};
      float w_[8] = {wf0.x, wf0.y, wf0.z, wf0.w, wf1.x, wf1.y, wf1.z, wf1.w};
#pragma unroll
      for (int i = 0; i < 4; ++i)
#pragma unroll
        for (int j = 0; j < 8; ++j)
          acc[i][j] = fmaf(a_[i], w_[j], acc[i][j]);
    }
    __syncthreads();
  }
#pragma unroll
  for (int i = 0; i < 4; ++i) {
    size_t row = (size_t)(m0 + (ty << 2) + i) * 128 + (tx << 3);
#pragma unroll
    for (int j = 0; j < 8; ++j)
      C[row + j] = f2b((acc[i][j] + bias[(tx << 3) + j]) * scale);
  }
}

// fused K+V projection, bf16 outputs
__global__ __launch_bounds__(256) void gemm_nt_kv_b16(
    const float* __restrict__ A,
    const float* __restrict__ Wk, const float* __restrict__ bk,
    const float* __restrict__ Wv, const float* __restrict__ bv,
    short* __restrict__ Ko, short* __restrict__ Vo, int M, int K) {
  __shared__ float as[16][68];
  __shared__ float wks[16][132];
  __shared__ float wvs[16][132];
  const int tid = threadIdx.x;
  const int m0 = blockIdx.x * 64;
  const int lm = tid >> 2;
  const int kq = (tid & 3) << 2;
  const int ty = tid >> 4;
  const int tx = tid & 15;
  float acck[4][8] = {};
  float accv[4][8] = {};
  for (int k0 = 0; k0 < K; k0 += 16) {
    float4 a4   = *(const float4*)(A + (size_t)(m0 + lm) * K + k0 + kq);
    float4 wk4  = *(const float4*)(Wk + (size_t)lm * K + k0 + kq);
    float4 wk4b = *(const float4*)(Wk + (size_t)(lm + 64) * K + k0 + kq);
    float4 wv4  = *(const float4*)(Wv + (size_t)lm * K + k0 + kq);
    float4 wv4b = *(const float4*)(Wv + (size_t)(lm + 64) * K + k0 + kq);
    as[kq + 0][lm] = a4.x;  as[kq + 1][lm] = a4.y;  as[kq + 2][lm] = a4.z;  as[kq + 3][lm] = a4.w;
    wks[kq + 0][lm] = wk4.x; wks[kq + 1][lm] = wk4.y; wks[kq + 2][lm] = wk4.z; wks[kq + 3][lm] = wk4.w;
    wks[kq + 0][lm + 64] = wk4b.x; wks[kq + 1][lm + 64] = wk4b.y;
    wks[kq + 2][lm + 64] = wk4b.z; wks[kq + 3][lm + 64] = wk4b.w;
    wvs[kq + 0][lm] = wv4.x; wvs[kq + 1][lm] = wv4.y; wvs[kq + 2][lm] = wv4.z; wvs[kq + 3][lm] = wv4.w;
    wvs[kq + 0][lm + 64] = wv4b.x; wvs[kq + 1][lm + 64] = wv4b.y;
    wvs[kq + 2][lm + 64] = wv4b.z; wvs[kq + 3][lm + 64] = wv4b.w;
    __syncthreads();
#pragma unroll
    for (int kk = 0; kk < 16; ++kk) {
      float4 af  = *(const float4*)&as[kk][ty << 2];
      float4 k0f = *(const float4*)&wks[kk][tx << 3];
      float4 k1f = *(const float4*)&wks[kk][(tx << 3) + 4];
      float4 v0f = *(const float4*)&wvs[kk][tx << 3];
      float4 v1f = *(const float4*)&wvs[kk][(tx << 3) + 4];
      float a_[4] = {af.x, af.y, af.z, af.w};
      float wk_[8] = {k0f.x, k0f.y, k0f.z, k0f.w, k1f.x, k1f.y, k1f.z, k1f.w};
      float wv_[8] = {v0f.x, v0f.y, v0f.z, v0f.w, v1f.x, v1f.y, v1f.z, v1f.w};
#pragma unroll
      for (int i = 0; i < 4; ++i)
#pragma unroll
        for (int j = 0; j < 8; ++j) {
          acck[i][j] = fmaf(a_[i], wk_[j], acck[i][j]);
          accv[i][j] = fmaf(a_[i], wv_[j], accv[i][j]);
        }
    }
    __syncthreads();
  }
#pragma unroll
  for (int i = 0; i < 4; ++i) {
    size_t row = (size_t)(m0 + (ty << 2) + i) * 128 + (tx << 3);
#pragma unroll
    for (int j = 0; j < 8; ++j) {
      Ko[row + j] = f2b(acck[i][j] + bk[(tx << 3) + j]);
      Vo[row + j] = f2b(accv[i][j] + bv[(tx << 3) + j]);
    }
  }
}

// ------------------------------------------------------- MFMA attention
// block per (b,s,h), 8 waves x 16 q-rows. Q pre-scaled by 1/sqrt(DH).
// mfma_f32_16x16x32_bf16 layouts:
//   A[m][k]:  lane l -> m = l&15, k = (l>>4)*8 + j   (8 bf16 / lane)
//   B[k][n]:  lane l -> n = l&15, k = (l>>4)*8 + j
//   C/D[m][n]: lane l -> n = l&15, m = (l>>4)*4 + reg
__global__ __launch_bounds__(512) void attn_mfma(
    const short* __restrict__ Qb, const short* __restrict__ Kb,
    const short* __restrict__ Vb, const float* __restrict__ bias,
    float* __restrict__ ctx) {
  __shared__ short vfrag[8][2][64][8];   // 16 KB, B-frag order for PV
  __shared__ short pbuf[8][16 * 40];     // 10 KB, per-wave P chunk [16 t][32 c], row pad 40

  const int tid = threadIdx.x;
  const int l = tid & 63;
  const int w = tid >> 6;                // wave id = m-tile
  const int lr = l & 15, lg = l >> 4;
  const int bid = blockIdx.x;
  const int h = bid & 3;
  const int s = (bid >> 2) % Sdim;
  const int b = bid / (Sdim * NHd);

  const size_t kvbase = ((size_t)(b * Sdim + s)) * Cdim * AHd + h * DHd;
  const size_t qbase  = ((size_t)(b * Sdim + s)) * Tdim * AHd + h * DHd;

  // stage V into frag order: vfrag[c>>5][d>>4][((c&31)>>3)*16 + (d&15)][c&7]
#pragma unroll
  for (int rep = 0; rep < 2; ++rep) {
    int chunk = tid * 2 + rep;           // 0..1023
    int c = chunk >> 2, q = chunk & 3;   // q: which 8-d group
    bf16x8 v8 = *(const bf16x8*)(Vb + kvbase + (size_t)c * AHd + q * 8);
    int kc = c >> 5, nt = q >> 1;
    int lanebase = ((c & 31) >> 3) * 16 + (q & 1) * 8;
    int j = c & 7;
#pragma unroll
    for (int e = 0; e < 8; ++e)
      vfrag[kc][nt][lanebase + e][j] = v8[e];
  }
  __syncthreads();

  // Q A-frag straight from global (16B/lane)
  bf16x8 qf = *(const bf16x8*)(Qb + qbase + (size_t)(w * 16 + lr) * AHd + lg * 8);

  const f32x4 zero = {0.f, 0.f, 0.f, 0.f};
  f32x4 sacc[16];
  // QK^T: K B-frags straight from global
#pragma unroll
  for (int nt = 0; nt < 16; ++nt) {
    bf16x8 kf = *(const bf16x8*)(Kb + kvbase + (size_t)(nt * 16 + lr) * AHd + lg * 8);
    sacc[nt] = __builtin_amdgcn_mfma_f32_16x16x32_bf16(qf, kf, zero, 0, 0, 0);
  }

  // + combined bias
  const float* bb = bias + ((size_t)(b * Sdim + s)) * Tdim * Cdim + (size_t)(w * 16) * Cdim;
#pragma unroll
  for (int nt = 0; nt < 16; ++nt)
#pragma unroll
    for (int r = 0; r < 4; ++r)
      sacc[nt][r] += bb[(lg * 4 + r) * Cdim + nt * 16 + lr];

  // softmax over c (16 in-lane tiles x 16 lanes), deferred normalization
  float mx[4], rinv[4];
#pragma unroll
  for (int r = 0; r < 4; ++r) {
    float m = sacc[0][r];
#pragma unroll
    for (int nt = 1; nt < 16; ++nt) m = fmaxf(m, sacc[nt][r]);
#pragma unroll
    for (int off = 1; off < 16; off <<= 1) m = fmaxf(m, __shfl_xor(m, off));
    mx[r] = m;
  }
#pragma unroll
  for (int nt = 0; nt < 16; ++nt)
#pragma unroll
    for (int r = 0; r < 4; ++r)
      sacc[nt][r] = __expf(sacc[nt][r] - mx[r]);
#pragma unroll
  for (int r = 0; r < 4; ++r) {
    float su = 0.f;
#pragma unroll
    for (int nt = 0; nt < 16; ++nt) su += sacc[nt][r];
#pragma unroll
    for (int off = 1; off < 16; off <<= 1) su += __shfl_xor(su, off);
    rinv[r] = 1.0f / su;
  }

  // PV: per 32-c chunk, hand P through wave-private LDS, 2 MFMA per chunk
  f32x4 cacc[2] = {zero, zero};
  short* pb = &pbuf[w][0];
#pragma unroll
  for (int kc = 0; kc < 8; ++kc) {
#pragma unroll
    for (int ntl = 0; ntl < 2; ++ntl) {
      int nt = kc * 2 + ntl;
#pragma unroll
      for (int r = 0; r < 4; ++r)
        pb[(lg * 4 + r) * 40 + ntl * 16 + lr] = f2b(sacc[nt][r]);
    }
    bf16x8 af = *(const bf16x8*)&pb[lr * 40 + lg * 8];
#pragma unroll
    for (int ntd = 0; ntd < 2; ++ntd) {
      bf16x8 vf = *(const bf16x8*)&vfrag[kc][ntd][l][0];
      cacc[ntd] = __builtin_amdgcn_mfma_f32_16x16x32_bf16(af, vf, cacc[ntd], 0, 0, 0);
    }
  }

  // store ctx (f32), scaled by 1/sum
  float* cb = ctx + qbase + (size_t)(w * 16) * AHd;
#pragma unroll
  for (int ntd = 0; ntd < 2; ++ntd)
#pragma unroll
    for (int r = 0; r < 4; ++r)
      cb[(size_t)(lg * 4 + r) * AHd + ntd * 16 + lr] = cacc[ntd][r] * rinv[r];
}

// ---------------------------------------------- f32 NT GEMM (out-projection)
__global__ __launch_bounds__(256) void gemm_nt(
    const float* __restrict__ A, const float* __restrict__ W,
    const float* __restrict__ bias, float* __restrict__ C,
    int M, int N, int K) {
  __shared__ float as[16][68];
  __shared__ float ws[16][132];
  const int tid = threadIdx.x;
  const int m0 = blockIdx.x * 64;
  const int n0 = blockIdx.y * 128;
  const int lm = tid >> 2;
  const int kq = (tid & 3) << 2;
  const int ty = tid >> 4;
  const int tx = tid & 15;
  float acc[4][8] = {};
  for (int k0 = 0; k0 < K; k0 += 16) {
    float4 a4  = *(const float4*)(A + (size_t)(m0 + lm) * K + k0 + kq);
    float4 w4  = *(const float4*)(W + (size_t)(n0 + lm) * K + k0 + kq);
    float4 w4b = *(const float4*)(W + (size_t)(n0 + lm + 64) * K + k0 + kq);
    as[kq + 0][lm] = a4.x;  as[kq + 1][lm] = a4.y;  as[kq + 2][lm] = a4.z;  as[kq + 3][lm] = a4.w;
    ws[kq + 0][lm] = w4.x;  ws[kq + 1][lm] = w4.y;  ws[kq + 2][lm] = w4.z;  ws[kq + 3][lm] = w4.w;
    ws[kq + 0][lm + 64] = w4b.x; ws[kq + 1][lm + 64] = w4b.y;
    ws[kq + 2][lm + 64] = w4b.z; ws[kq + 3][lm + 64] = w4b.w;
    __syncthreads();
#pragma unroll
    for (int kk = 0; kk < 16; ++kk) {
      float4 af  = *(const float4*)&as[kk][ty << 2];
      float4 wf0 = *(const float4*)&ws[kk][tx << 3];
      float4 wf1 = *(const float4*)&ws[kk][(tx << 3) + 4];
      float a_[4] = {af.x, af.y, af.z, af.w};
      float w_[8] = {wf0.x, wf0.y, wf0.z, wf0.w, wf1.x, wf1.y, wf1.z, wf1.w};
#pragma unroll
      for (int i = 0; i < 4; ++i)
#pragma unroll
        for (int j = 0; j < 8; ++j)
          acc[i][j] = fmaf(a_[i], w_[j], acc[i][j]);
    }
    __syncthreads();
  }
#pragma unroll
  for (int i = 0; i < 4; ++i) {
    size_t row = (size_t)(m0 + (ty << 2) + i) * N + n0 + (tx << 3);
#pragma unroll
    for (int j = 0; j < 8; ++j)
      C[row + j] = acc[i][j] + bias[n0 + (tx << 3) + j];
  }
}

// ------------------------------------------------------------------ launch
extern "C" void kernel_launch(void* const* d_in, const int* in_sizes, int n_in,
                              void* d_out, int out_size, void* d_ws, size_t ws_size,
                              hipStream_t stream) {
  const float* hs     = (const float*)d_in[0];
  const float* se     = (const float*)d_in[1];
  const float* mask   = (const float*)d_in[2];
  const float* stdist = (const float*)d_in[3];
  const float* stdoy  = (const float*)d_in[4];
  const float* Wq = (const float*)d_in[5];
  const float* bq = (const float*)d_in[6];
  const float* Wk = (const float*)d_in[7];
  const float* bk = (const float*)d_in[8];
  const float* Wv = (const float*)d_in[9];
  const float* bv = (const float*)d_in[10];
  const float* Wo = (const float*)d_in[11];
  const float* bo = (const float*)d_in[12];
  const float* c_s  = (const float*)d_in[13];
  const float* w1_s = (const float*)d_in[14];
  const float* w2_s = (const float*)d_in[15];
  const float* c_t  = (const float*)d_in[16];
  const float* w1_t = (const float*)d_in[17];
  const float* w2_t = (const float*)d_in[18];
  const float* c_d  = (const float*)d_in[19];
  const float* w1_d = (const float*)d_in[20];
  const float* w2_d = (const float*)d_in[21];
  const float* sls  = (const float*)d_in[22];
  const float* tls  = (const float*)d_in[23];
  float* out = (float*)d_out;

  float* ws = (float*)d_ws;
  const size_t BTC  = (size_t)Bdim * Tdim * Cdim;            // 131072
  const size_t BSTC = (size_t)Bdim * Sdim * Tdim * Cdim;     // 13107200
  const size_t NQ   = (size_t)Bdim * Sdim * Tdim * AHd;      // 6553600
  const size_t NKV  = (size_t)Bdim * Sdim * Cdim * AHd;      // 13107200

  float* sb   = ws;
  float* tb   = sb + BTC;
  float* dbm  = tb + BTC;
  float* bias = dbm + BTC;            // (B,S,T,C) f32
  short* Qb   = (short*)(bias + BSTC);        // bf16 (B,S,T,128)
  short* Kb   = Qb + NQ;                      // bf16 (B,S,C,128)
  short* Vb   = Kb + NKV;
  float* ctxp = (float*)(Vb + NKV);           // f32 (B,S,T,128)

  const int MQ  = Bdim * Sdim * Tdim;   // 51200
  const int MKV = Bdim * Sdim * Cdim;   // 102400

  fire_bias_kernel<<<(Bdim * Tdim * Cdim + 255) / 256, 256, 0, stream>>>(
      stdist, stdoy, mask, c_s, w1_s, w2_s, c_t, w1_t, w2_t, c_d, w1_d, w2_d, sb, tb, dbm);

  bias_expand<<<dim3(Tdim * Cdim / 1024, Bdim * Sdim), 256, 0, stream>>>(
      sb, tb, dbm, sls, tls, bias);

  gemm_nt_b16<<<dim3(MQ / 64), 256, 0, stream>>>(hs, Wq, bq, Qb, MQ, 256,
                                                 0.17677669529663687f);
  gemm_nt_kv_b16<<<dim3(MKV / 64), 256, 0, stream>>>(se, Wk, bk, Wv, bv, Kb, Vb, MKV, 256);

  attn_mfma<<<dim3(Bdim * Sdim * NHd), 512, 0, stream>>>(Qb, Kb, Vb, bias, ctxp);

  gemm_nt<<<dim3(MQ / 64, 2), 256, 0, stream>>>(ctxp, Wo, bo, out, MQ, 256, 128);
}